// Round 6
// baseline (116.064 us; speedup 1.0000x reference)
//
#include <hip/hip_runtime.h>
#include <math.h>

#define NN 4096
#define DD 512
#define MARGINF 1.0f
#define NCLS 64
#define MAXM 160
#define TRI (MAXM * (MAXM - 1) / 2)    // 12720
#define PBLK 32                         // 128-row panels
#define NBLK2 (PBLK * (PBLK + 1) / 2)   // 528 triangular 128x128 tiles
#define NSLICE 4                        // pair2 blocks per class

typedef __attribute__((ext_vector_type(8))) short bf16x8;  // 8 bf16 (4 VGPRs)
typedef __attribute__((ext_vector_type(4))) float f32x4;   // 4 fp32 acc

// ws layout (float indices):
#define WS_SQ   0         // float[4096] ||x_i||^2
#define WS_NS   4096      // float[4096] neg_sum
#define WS_LOSS 8192      // float[1] sum hinge^2
#define WS_CTR  8193      // uint[1] pair2 completion counter
#define WS_LENP 8194      // float[1] sum over classes mc*(mc-1)
#define WS_RK   8320      // int[4096] rank within class (atomic-free)
#define WS_MEM  12416     // int[64*160] class member lists (rank-indexed)
#define WS_XF   32768     // ushort[4096*512] FRAGMENT-MAJOR bf16 X (4 MB)
                          //   frag(r16,kb) = 1KB at short-off (r16*16+kb)*512;
                          //   element lane*8+e  (lane=q*16+m, e=k&7)
#define WS_PD   1081344   // float[64*TRI] positive-pair distances

__device__ __forceinline__ unsigned short f2bf(float f) {
    unsigned u = __float_as_uint(f);
    u += 0x7fffu + ((u >> 16) & 1u);   // round-to-nearest-even
    return (unsigned short)(u >> 16);
}

// Row norms + fragment-major bf16 conversion + ATOMIC-FREE class ranks.
__global__ __launch_bounds__(256) void prep_kernel(const float* __restrict__ X,
                                                   const int* __restrict__ tgt,
                                                   float* __restrict__ ws) {
    __shared__ int tg[NN];   // 16 KB
    const int tid = threadIdx.x;
    for (int j = tid; j < NN; j += 256) tg[j] = tgt[j];

    const int wv = tid >> 6, lane = tid & 63;
    const int row = blockIdx.x * 4 + wv;
    const float4* xr = (const float4*)(X + (size_t)row * DD);
    float4 a = xr[2 * lane], b = xr[2 * lane + 1];
    float s = a.x * a.x + a.y * a.y + a.z * a.z + a.w * a.w
            + b.x * b.x + b.y * b.y + b.z * b.z + b.w * b.w;
#pragma unroll
    for (int off = 32; off; off >>= 1) s += __shfl_down(s, off, 64);

    ushort4 pa = {f2bf(a.x), f2bf(a.y), f2bf(a.z), f2bf(a.w)};
    ushort4 pb = {f2bf(b.x), f2bf(b.y), f2bf(b.z), f2bf(b.w)};
    const int r16 = row >> 4, m = row & 15;
    const int kb = lane >> 2, q = lane & 3;
    ushort4* dst = (ushort4*)((unsigned short*)(ws + WS_XF)
                              + ((size_t)(r16 * 16 + kb) * 64 + q * 16 + m) * 8);
    dst[0] = pa;
    dst[1] = pb;

    __syncthreads();
    const int myc = tg[row];
    int cnt = 0;
    for (int j = lane; j < row; j += 64) cnt += (tg[j] == myc) ? 1 : 0;
#pragma unroll
    for (int off = 32; off; off >>= 1) cnt += __shfl_down(cnt, off, 64);
    if (lane == 0) {
        ws[WS_SQ + row] = s;
        ws[WS_NS + row] = 0.0f;
        ((int*)(ws + WS_RK))[row] = cnt;
        if (cnt < MAXM) ((int*)(ws + WS_MEM))[myc * MAXM + cnt] = row;
    }
    if (blockIdx.x == 0 && tid == 0) {
        ws[WS_LOSS] = 0.0f;
        ((unsigned*)ws)[WS_CTR] = 0u;
        ws[WS_LENP] = 0.0f;
    }
}

// Gram via bf16 MFMA. 128x128 tile per block (528 triangular blocks, XCD-
// swizzled, ALL resident: 3 blk/CU x 48 KB LDS), 4 waves x 64x64 (ds:MFMA
// = 1:2, halves LDS-read + DMA instr counts vs 64^2 tiles).
// DISTANCE-2 COUNTED-VMCNT PIPELINE (T4 minimal form): stage chunk t+2 via
// global_load_lds while computing chunk t from buf[t%3]; end each chunk with
// s_waitcnt vmcnt(4) (NOT 0 -- chunk t+2's 4 DMAs stay in flight across the
// barrier) + raw s_barrier. Race-free: every wave issues exactly 4 DMAs per
// chunk, so per-wave vmcnt(4) == "my chunk-(t+1) DMAs done"; the barrier
// then publishes all 16 frags. The buffer DMA'd at t+1 ((t+3)%3 == t%3) was
// last read at chunk t, fully consumed before this barrier.
__global__ __launch_bounds__(256, 3) void negsum_kernel(const int* __restrict__ tgt,
                                                        float* __restrict__ ws) {
    __shared__ unsigned short lds[3][16][512];   // [buf][frag: 0-7 A, 8-15 B] 48 KB
    // XCD-chunked bijective swizzle: 528 = 8 * 66.
    const int bidx = (blockIdx.x & 7) * 66 + (blockIdx.x >> 3);
    int bj = (int)((sqrtf(8.0f * (float)bidx + 1.0f) - 1.0f) * 0.5f);
    while (bj * (bj + 1) / 2 > bidx) --bj;
    while ((bj + 1) * (bj + 2) / 2 <= bidx) ++bj;
    const int bi = bidx - bj * (bj + 1) / 2;   // bi <= bj
    const int i0 = bi * 128, j0 = bj * 128;

    const int tid = threadIdx.x;
    const int w = tid >> 6, lane = tid & 63;
    const int m_ = lane & 15, q = lane >> 4;
    const int wr = (w & 1) * 64, wc = (w >> 1) * 64;   // wave's 64x64 quadrant
    const unsigned short* Xf = (const unsigned short*)(ws + WS_XF);
    const int air0 = i0 >> 4, bjr0 = j0 >> 4;

    // this wave stages frags {4w..4w+3} of each chunk (frag f<8: A row-block
    // air0+f; f>=8: B row-block bjr0+f-8)
    int fr16[4];
#pragma unroll
    for (int s = 0; s < 4; ++s) {
        const int f = w * 4 + s;
        fr16[s] = (f < 8) ? (air0 + f) : (bjr0 + (f - 8));
    }

#define DMA_CHUNK(kb_, buf_)                                                   \
    {                                                                          \
        _Pragma("unroll")                                                      \
        for (int s = 0; s < 4; ++s) {                                          \
            const unsigned short* gp =                                         \
                Xf + ((size_t)fr16[s] * 16 + (kb_)) * 512 + lane * 8;          \
            __builtin_amdgcn_global_load_lds(                                  \
                (const __attribute__((address_space(1))) int*)gp,              \
                (__attribute__((address_space(3))) int*)(&lds[buf_][w * 4 + s][0]), \
                16, 0, 0);                                                     \
        }                                                                      \
    }

    f32x4 acc[4][4] = {};

    // prologue: chunks 0,1 in flight; wait only for chunk 0 (vmcnt 4 keeps
    // chunk 1's 4 DMAs outstanding across the barrier)
    DMA_CHUNK(0, 0)
    DMA_CHUNK(1, 1)
    asm volatile("s_waitcnt vmcnt(4)" ::: "memory");
    __builtin_amdgcn_s_barrier();

#pragma unroll
    for (int t = 0; t < 16; ++t) {
        const int cur = t % 3;
        if (t < 14) DMA_CHUNK(t + 2, (t + 2) % 3)
        bf16x8 af[4], bf[4];
#pragma unroll
        for (int u = 0; u < 4; ++u)
            af[u] = *(const bf16x8*)&lds[cur][(w & 1) * 4 + u][lane * 8];
#pragma unroll
        for (int v = 0; v < 4; ++v)
            bf[v] = *(const bf16x8*)&lds[cur][8 + (w >> 1) * 4 + v][lane * 8];
#pragma unroll
        for (int u = 0; u < 4; ++u)
#pragma unroll
            for (int v = 0; v < 4; ++v)
                acc[u][v] = __builtin_amdgcn_mfma_f32_16x16x32_bf16(
                    af[u], bf[v], acc[u][v], 0, 0, 0);
        if (t < 14) {
            asm volatile("s_waitcnt vmcnt(4)" ::: "memory");   // chunk t+1 ready
            __builtin_amdgcn_s_barrier();
        } else if (t == 14) {
            asm volatile("s_waitcnt vmcnt(0)" ::: "memory");   // last chunk ready
            __builtin_amdgcn_s_barrier();
        }
    }
#undef DMA_CHUNK

    // epilogue: C/D map col=lane&15, row=(lane>>4)*4+reg
    const float* sq = ws + WS_SQ;
    float* ns = ws + WS_NS;
    const int* rk = (const int*)(ws + WS_RK);
    float* posd = ws + WS_PD;
    float sjv[4]; int tjv[4], jv[4];
#pragma unroll
    for (int v = 0; v < 4; ++v) {
        int j = j0 + wc + v * 16 + m_;
        jv[v] = j;
        sjv[v] = sq[j];
        tjv[v] = tgt[j];
    }
    float colp[4] = {0.0f, 0.0f, 0.0f, 0.0f};
#pragma unroll
    for (int u = 0; u < 4; ++u) {
#pragma unroll
        for (int r = 0; r < 4; ++r) {
            const int i = i0 + wr + u * 16 + q * 4 + r;
            const float si = sq[i];
            const int ti = tgt[i];
            float rp = 0.0f;
#pragma unroll
            for (int v = 0; v < 4; ++v) {
                float d2 = si + sjv[v] - 2.0f * acc[u][v][r];
                float dist = d2 > 0.0f ? sqrtf(d2) : 0.0f;
                if (tjv[v] != ti) {
                    float e = __expf(MARGINF - dist);
                    rp += e;
                    colp[v] += e;
                } else if (i < jv[v]) {
                    int ra = rk[i], rb = rk[jv[v]];
                    if (ra < MAXM && rb < MAXM) {
                        int hi = ra > rb ? ra : rb;
                        int lo = ra > rb ? rb : ra;
                        posd[ti * TRI + hi * (hi - 1) / 2 + lo] = dist;
                    }
                }
            }
            rp += __shfl_xor(rp, 1, 64);
            rp += __shfl_xor(rp, 2, 64);
            rp += __shfl_xor(rp, 4, 64);
            rp += __shfl_xor(rp, 8, 64);
            if (m_ == 0) atomicAdd(&ns[i], rp);
        }
    }
    if (bi != bj) {   // symmetric contribution: G[j][i] == G[i][j]
#pragma unroll
        for (int v = 0; v < 4; ++v) {
            float cp = colp[v];
            cp += __shfl_xor(cp, 16, 64);
            cp += __shfl_xor(cp, 32, 64);
            if (q == 0) atomicAdd(&ns[jv[v]], cp);
        }
    }
}

// Positive pairs from stored distances; NSLICE blocks per class for occupancy;
// last block finalizes out = loss / len_p.
__global__ __launch_bounds__(256) void pair2_kernel(const int* __restrict__ tgt,
                                                    float* __restrict__ ws,
                                                    float* __restrict__ out) {
    __shared__ float wsum[4];
    __shared__ int csum[4];
    __shared__ bool last;
    const int c = blockIdx.x >> 2;
    const int sl = blockIdx.x & 3;
    const int tid = threadIdx.x;
    const int wv = tid >> 6, lane = tid & 63;

    int ccount = 0;
    for (int j = tid; j < NN; j += 256) ccount += (tgt[j] == c) ? 1 : 0;
#pragma unroll
    for (int off = 32; off; off >>= 1) ccount += __shfl_down(ccount, off, 64);
    if (lane == 0) csum[wv] = ccount;
    __syncthreads();
    int mc = csum[0] + csum[1] + csum[2] + csum[3];
    if (mc > MAXM) mc = MAXM;
    const int P = mc * (mc - 1) / 2;

    const int* mem = (const int*)(ws + WS_MEM) + c * MAXM;
    const float* pd = ws + WS_PD + c * TRI;
    const float* ns = ws + WS_NS;
    float lsum = 0.0f;
    for (int p = tid + sl * 256; p < P; p += 256 * NSLICE) {
        int b = (int)((1.0f + sqrtf(1.0f + 8.0f * (float)p)) * 0.5f);
        while (b * (b - 1) / 2 > p) --b;
        while ((b + 1) * b / 2 <= p) ++b;
        const int a = p - b * (b - 1) / 2;
        const float dist = pd[b * (b - 1) / 2 + a];
        const int i = mem[a], j = mem[b];
        float J = __logf(ns[i] + ns[j]) + dist;
        float h = fmaxf(J, 0.0f);
        lsum += h * h;
    }
#pragma unroll
    for (int off = 32; off; off >>= 1) lsum += __shfl_xor(lsum, off, 64);
    if (lane == 0) wsum[wv] = lsum;
    __syncthreads();
    if (tid == 0) {
        float s = wsum[0] + wsum[1] + wsum[2] + wsum[3];
        if (s != 0.0f) atomicAdd(&ws[WS_LOSS], s);
        if (sl == 0) atomicAdd(&ws[WS_LENP], (float)(mc * (mc - 1)));
        __threadfence();
        unsigned d = atomicAdd((unsigned*)ws + WS_CTR, 1u);
        last = (d == NCLS * NSLICE - 1);
    }
    __syncthreads();
    if (last && tid == 0) {
        float total = atomicAdd(&ws[WS_LOSS], 0.0f);   // device-scope reads
        float lp = atomicAdd(&ws[WS_LENP], 0.0f);
        out[0] = total / lp;
    }
}

extern "C" void kernel_launch(void* const* d_in, const int* in_sizes, int n_in,
                              void* d_out, int out_size, void* d_ws, size_t ws_size,
                              hipStream_t stream) {
    const float* X  = (const float*)d_in[0];
    const int*  tgt = (const int*)d_in[1];
    float* ws  = (float*)d_ws;
    float* out = (float*)d_out;

    hipLaunchKernelGGL(prep_kernel, dim3(NN / 4), dim3(256), 0, stream, X, tgt, ws);
    hipLaunchKernelGGL(negsum_kernel, dim3(NBLK2), dim3(256), 0, stream, tgt, ws);
    hipLaunchKernelGGL(pair2_kernel, dim3(NCLS * NSLICE), dim3(256), 0, stream, tgt, ws, out);
}

// Round 7
// 107.762 us; speedup vs baseline: 1.0770x; 1.0770x over previous
//
#include <hip/hip_runtime.h>
#include <math.h>

#define NN 4096
#define DD 512
#define MARGINF 1.0f
#define NCLS 64
#define MAXM 160
#define TRI (MAXM * (MAXM - 1) / 2)   // 12720
#define NBLK 2080                     // 64*65/2 triangular 64-tiles
#define NSLICE 4                      // pair2 blocks per class

typedef __attribute__((ext_vector_type(8))) short bf16x8;  // 8 bf16 (4 VGPRs)
typedef __attribute__((ext_vector_type(4))) float f32x4;   // 4 fp32 acc

// ws layout (float indices):
#define WS_SQ   0         // float[4096] ||x_i||^2
#define WS_NS   4096      // float[4096] neg_sum
#define WS_LOSS 8192      // float[1] sum hinge^2
#define WS_CTR  8193      // uint[1] pair2 completion counter
#define WS_LENP 8194      // float[1] sum over classes mc*(mc-1)
#define WS_RK   8320      // int[4096] rank within class (atomic-free)
#define WS_MEM  12416     // int[64*160] class member lists (rank-indexed)
#define WS_XF   32768     // ushort[4096*512] FRAGMENT-MAJOR bf16 X (4 MB)
                          //   frag(r16,kb) = 1KB at short-off (r16*16+kb)*512;
                          //   element lane*8+e  (lane=q*16+m, e=k&7)
#define WS_PD   1081344   // float[64*TRI] positive-pair distances

__device__ __forceinline__ unsigned short f2bf(float f) {
    unsigned u = __float_as_uint(f);
    u += 0x7fffu + ((u >> 16) & 1u);   // round-to-nearest-even
    return (unsigned short)(u >> 16);
}

// Row norms + fragment-major bf16 conversion + ATOMIC-FREE class ranks.
__global__ __launch_bounds__(256) void prep_kernel(const float* __restrict__ X,
                                                   const int* __restrict__ tgt,
                                                   float* __restrict__ ws) {
    __shared__ int tg[NN];   // 16 KB
    const int tid = threadIdx.x;
    for (int j = tid; j < NN; j += 256) tg[j] = tgt[j];

    const int wv = tid >> 6, lane = tid & 63;
    const int row = blockIdx.x * 4 + wv;
    const float4* xr = (const float4*)(X + (size_t)row * DD);
    float4 a = xr[2 * lane], b = xr[2 * lane + 1];
    float s = a.x * a.x + a.y * a.y + a.z * a.z + a.w * a.w
            + b.x * b.x + b.y * b.y + b.z * b.z + b.w * b.w;
#pragma unroll
    for (int off = 32; off; off >>= 1) s += __shfl_down(s, off, 64);

    ushort4 pa = {f2bf(a.x), f2bf(a.y), f2bf(a.z), f2bf(a.w)};
    ushort4 pb = {f2bf(b.x), f2bf(b.y), f2bf(b.z), f2bf(b.w)};
    const int r16 = row >> 4, m = row & 15;
    const int kb = lane >> 2, q = lane & 3;
    ushort4* dst = (ushort4*)((unsigned short*)(ws + WS_XF)
                              + ((size_t)(r16 * 16 + kb) * 64 + q * 16 + m) * 8);
    dst[0] = pa;
    dst[1] = pb;

    __syncthreads();
    const int myc = tg[row];
    int cnt = 0;
    for (int j = lane; j < row; j += 64) cnt += (tg[j] == myc) ? 1 : 0;
#pragma unroll
    for (int off = 32; off; off >>= 1) cnt += __shfl_down(cnt, off, 64);
    if (lane == 0) {
        ws[WS_SQ + row] = s;
        ws[WS_NS + row] = 0.0f;
        ((int*)(ws + WS_RK))[row] = cnt;
        if (cnt < MAXM) ((int*)(ws + WS_MEM))[myc * MAXM + cnt] = row;
    }
    if (blockIdx.x == 0 && tid == 0) {
        ws[WS_LOSS] = 0.0f;
        ((unsigned*)ws)[WS_CTR] = 0u;
        ws[WS_LENP] = 0.0f;
    }
}

// Gram via bf16 MFMA. R5 geometry EXACTLY (64x64 tile, 2080 XCD-swizzled
// blocks, wave = 32x32, LDS panel sharing -> 266 MB fetch), ONE change:
// DISTANCE-2 COUNTED-VMCNT schedule (correctness-validated in R6). 3 LDS
// buffers (24 KB -> 6 blk/CU = 24 waves/CU resident, 8.1 blk/CU grid depth).
// Per chunk each wave issues exactly 2 DMAs (its 2 frags); end-of-chunk is
// s_waitcnt vmcnt(2) -- NOT 0 -- so chunk t+2's DMAs stay in flight across
// the barrier and the wait covers only chunk t+1, issued a full chunk ago.
// Buffer reuse is safe: buf[(t+2)%3] was last read at chunk t-1, and all
// waves crossed the end-of-(t-1) barrier before t's DMA issues into it.
__global__ __launch_bounds__(256, 6) void negsum_kernel(const int* __restrict__ tgt,
                                                        float* __restrict__ ws) {
    __shared__ unsigned short lds[3][8][512];   // [buf][frag: 0-3 A, 4-7 B] 24 KB
    // XCD-chunked bijective swizzle: 2080 = 8 * 260.
    const int bidx = (blockIdx.x & 7) * 260 + (blockIdx.x >> 3);
    int bj = (int)((sqrtf(8.0f * (float)bidx + 1.0f) - 1.0f) * 0.5f);
    while (bj * (bj + 1) / 2 > bidx) --bj;
    while ((bj + 1) * (bj + 2) / 2 <= bidx) ++bj;
    const int bi = bidx - bj * (bj + 1) / 2;   // bi <= bj
    const int i0 = bi * 64, j0 = bj * 64;

    const int tid = threadIdx.x;
    const int w = tid >> 6, lane = tid & 63;
    const int m_ = lane & 15, q = lane >> 4;
    const int wr = (w & 1) * 32, wc = (w >> 1) * 32;   // wave's 32x32 quadrant
    const unsigned short* Xf = (const unsigned short*)(ws + WS_XF);
    const int air0 = i0 >> 4, bjr0 = j0 >> 4;

    // this wave stages frags {2w, 2w+1} of each chunk (frag f<4: A row-block
    // air0+f; f>=4: B row-block bjr0+f-4)
    int fr16[2];
#pragma unroll
    for (int s = 0; s < 2; ++s) {
        const int f = w * 2 + s;
        fr16[s] = (f < 4) ? (air0 + f) : (bjr0 + (f - 4));
    }

#define DMA_CHUNK(kb_, buf_)                                                   \
    {                                                                          \
        _Pragma("unroll")                                                      \
        for (int s = 0; s < 2; ++s) {                                          \
            const unsigned short* gp =                                         \
                Xf + ((size_t)fr16[s] * 16 + (kb_)) * 512 + lane * 8;          \
            __builtin_amdgcn_global_load_lds(                                  \
                (const __attribute__((address_space(1))) int*)gp,              \
                (__attribute__((address_space(3))) int*)(&lds[buf_][w * 2 + s][0]), \
                16, 0, 0);                                                     \
        }                                                                      \
    }

    f32x4 acc[2][2] = {};

    // prologue: chunks 0,1 in flight; wait only chunk 0 (vmcnt(2) keeps
    // chunk 1's 2 DMAs outstanding across the barrier)
    DMA_CHUNK(0, 0)
    DMA_CHUNK(1, 1)
    asm volatile("s_waitcnt vmcnt(2)" ::: "memory");
    __builtin_amdgcn_s_barrier();

#pragma unroll
    for (int t = 0; t < 16; ++t) {
        const int cur = t % 3;
        if (t < 14) DMA_CHUNK(t + 2, (t + 2) % 3)
        bf16x8 af[2], bf[2];
#pragma unroll
        for (int u = 0; u < 2; ++u)
            af[u] = *(const bf16x8*)&lds[cur][(w & 1) * 2 + u][lane * 8];
#pragma unroll
        for (int v = 0; v < 2; ++v)
            bf[v] = *(const bf16x8*)&lds[cur][4 + (w >> 1) * 2 + v][lane * 8];
        acc[0][0] = __builtin_amdgcn_mfma_f32_16x16x32_bf16(af[0], bf[0], acc[0][0], 0, 0, 0);
        acc[0][1] = __builtin_amdgcn_mfma_f32_16x16x32_bf16(af[0], bf[1], acc[0][1], 0, 0, 0);
        acc[1][0] = __builtin_amdgcn_mfma_f32_16x16x32_bf16(af[1], bf[0], acc[1][0], 0, 0, 0);
        acc[1][1] = __builtin_amdgcn_mfma_f32_16x16x32_bf16(af[1], bf[1], acc[1][1], 0, 0, 0);
        if (t < 14) {
            asm volatile("s_waitcnt vmcnt(2)" ::: "memory");   // chunk t+1 ready
            __builtin_amdgcn_s_barrier();
        } else if (t == 14) {
            asm volatile("s_waitcnt vmcnt(0)" ::: "memory");   // last chunk ready
            __builtin_amdgcn_s_barrier();
        }
    }
#undef DMA_CHUNK

    // epilogue: C/D map col=lane&15, row=(lane>>4)*4+reg
    const float* sq = ws + WS_SQ;
    float* ns = ws + WS_NS;
    const int* rk = (const int*)(ws + WS_RK);
    float* posd = ws + WS_PD;
    float sjv[2]; int tjv[2], jv[2];
#pragma unroll
    for (int v = 0; v < 2; ++v) {
        int j = j0 + wc + v * 16 + m_;
        jv[v] = j;
        sjv[v] = sq[j];
        tjv[v] = tgt[j];
    }
    float colp[2] = {0.0f, 0.0f};
#pragma unroll
    for (int u = 0; u < 2; ++u) {
#pragma unroll
        for (int r = 0; r < 4; ++r) {
            const int i = i0 + wr + u * 16 + q * 4 + r;
            const float si = sq[i];
            const int ti = tgt[i];
            float rp = 0.0f;
#pragma unroll
            for (int v = 0; v < 2; ++v) {
                float d2 = si + sjv[v] - 2.0f * acc[u][v][r];
                float dist = d2 > 0.0f ? sqrtf(d2) : 0.0f;
                if (tjv[v] != ti) {
                    float e = __expf(MARGINF - dist);
                    rp += e;
                    colp[v] += e;
                } else if (i < jv[v]) {
                    int ra = rk[i], rb = rk[jv[v]];
                    if (ra < MAXM && rb < MAXM) {
                        int hi = ra > rb ? ra : rb;
                        int lo = ra > rb ? rb : ra;
                        posd[ti * TRI + hi * (hi - 1) / 2 + lo] = dist;
                    }
                }
            }
            rp += __shfl_xor(rp, 1, 64);
            rp += __shfl_xor(rp, 2, 64);
            rp += __shfl_xor(rp, 4, 64);
            rp += __shfl_xor(rp, 8, 64);
            if (m_ == 0) atomicAdd(&ns[i], rp);
        }
    }
    if (bi != bj) {   // symmetric contribution: G[j][i] == G[i][j]
#pragma unroll
        for (int v = 0; v < 2; ++v) {
            float cp = colp[v];
            cp += __shfl_xor(cp, 16, 64);
            cp += __shfl_xor(cp, 32, 64);
            if (q == 0) atomicAdd(&ns[jv[v]], cp);
        }
    }
}

// Positive pairs from stored distances; NSLICE blocks per class for occupancy;
// last block finalizes out = loss / len_p.
__global__ __launch_bounds__(256) void pair2_kernel(const int* __restrict__ tgt,
                                                    float* __restrict__ ws,
                                                    float* __restrict__ out) {
    __shared__ float wsum[4];
    __shared__ int csum[4];
    __shared__ bool last;
    const int c = blockIdx.x >> 2;
    const int sl = blockIdx.x & 3;
    const int tid = threadIdx.x;
    const int wv = tid >> 6, lane = tid & 63;

    int ccount = 0;
    for (int j = tid; j < NN; j += 256) ccount += (tgt[j] == c) ? 1 : 0;
#pragma unroll
    for (int off = 32; off; off >>= 1) ccount += __shfl_down(ccount, off, 64);
    if (lane == 0) csum[wv] = ccount;
    __syncthreads();
    int mc = csum[0] + csum[1] + csum[2] + csum[3];
    if (mc > MAXM) mc = MAXM;
    const int P = mc * (mc - 1) / 2;

    const int* mem = (const int*)(ws + WS_MEM) + c * MAXM;
    const float* pd = ws + WS_PD + c * TRI;
    const float* ns = ws + WS_NS;
    float lsum = 0.0f;
    for (int p = tid + sl * 256; p < P; p += 256 * NSLICE) {
        int b = (int)((1.0f + sqrtf(1.0f + 8.0f * (float)p)) * 0.5f);
        while (b * (b - 1) / 2 > p) --b;
        while ((b + 1) * b / 2 <= p) ++b;
        const int a = p - b * (b - 1) / 2;
        const float dist = pd[b * (b - 1) / 2 + a];
        const int i = mem[a], j = mem[b];
        float J = __logf(ns[i] + ns[j]) + dist;
        float h = fmaxf(J, 0.0f);
        lsum += h * h;
    }
#pragma unroll
    for (int off = 32; off; off >>= 1) lsum += __shfl_xor(lsum, off, 64);
    if (lane == 0) wsum[wv] = lsum;
    __syncthreads();
    if (tid == 0) {
        float s = wsum[0] + wsum[1] + wsum[2] + wsum[3];
        if (s != 0.0f) atomicAdd(&ws[WS_LOSS], s);
        if (sl == 0) atomicAdd(&ws[WS_LENP], (float)(mc * (mc - 1)));
        __threadfence();
        unsigned d = atomicAdd((unsigned*)ws + WS_CTR, 1u);
        last = (d == NCLS * NSLICE - 1);
    }
    __syncthreads();
    if (last && tid == 0) {
        float total = atomicAdd(&ws[WS_LOSS], 0.0f);   // device-scope reads
        float lp = atomicAdd(&ws[WS_LENP], 0.0f);
        out[0] = total / lp;
    }
}

extern "C" void kernel_launch(void* const* d_in, const int* in_sizes, int n_in,
                              void* d_out, int out_size, void* d_ws, size_t ws_size,
                              hipStream_t stream) {
    const float* X  = (const float*)d_in[0];
    const int*  tgt = (const int*)d_in[1];
    float* ws  = (float*)d_ws;
    float* out = (float*)d_out;

    hipLaunchKernelGGL(prep_kernel, dim3(NN / 4), dim3(256), 0, stream, X, tgt, ws);
    hipLaunchKernelGGL(negsum_kernel, dim3(NBLK), dim3(256), 0, stream, tgt, ws);
    hipLaunchKernelGGL(pair2_kernel, dim3(NCLS * NSLICE), dim3(256), 0, stream, tgt, ws, out);
}